// Round 9
// baseline (143.863 us; speedup 1.0000x reference)
//
#include <hip/hip_runtime.h>
#include <hip/hip_bf16.h>
#include <cstdint>
#include <cstddef>

typedef __attribute__((ext_vector_type(4))) float f32x4;
typedef __attribute__((ext_vector_type(8))) short s16x8;
typedef __attribute__((ext_vector_type(4))) unsigned int u32x4;

#define SDIM 4096
#define DDIM 256
#define NCH 8

#define GLOAD_LDS16(g, s)                                                      \
  __builtin_amdgcn_global_load_lds(                                            \
      (const __attribute__((address_space(1))) void*)(g),                      \
      (__attribute__((address_space(3))) void*)(s), 16, 0, 0)

// round-to-nearest-even f32 -> bf16 bits
__device__ __forceinline__ unsigned short cvt_bf16(float f) {
  union { float f; unsigned int u; } v;
  v.f = f;
  unsigned int u = v.u;
  unsigned int r = (u + 0x7FFFu + ((u >> 16) & 1u)) >> 16;
  return (unsigned short)r;
}

__device__ __forceinline__ float bf2f(unsigned short s) {
  union { unsigned int u; float f; } v;
  v.u = ((unsigned int)s) << 16;
  return v.f;
}

// ---------------- W -> bf16 ----------------
__global__ __launch_bounds__(256) void k_convw(const float* __restrict__ W,
                                               unsigned short* __restrict__ Wb) {
  int i = (blockIdx.x * 256 + threadIdx.x) * 8;
  f32x4 a = *(const f32x4*)(W + i);
  f32x4 b = *(const f32x4*)(W + i + 4);
  s16x8 o;
#pragma unroll
  for (int j = 0; j < 4; ++j) {
    o[j] = (short)cvt_bf16(a[j]);
    o[4 + j] = (short)cvt_bf16(b[j]);
  }
  *(s16x8*)(Wb + i) = o;
}

// ---------------- fused: Kp = (E @ W^T) * (log2e/16)  AND  Vt = E^T (bf16) ------------
// One pass over E (it was read twice before). Block = 64 rows; GEMM via MFMA as before;
// the bf16 A-fragments are also parked in an LDS tile [64][264] and transposed out to Vt.
__global__ __launch_bounds__(256) void k_projv(const float* __restrict__ E,
                                               const unsigned short* __restrict__ Wb,
                                               unsigned short* __restrict__ Kp,
                                               unsigned short* __restrict__ Vt) {
  __shared__ unsigned short tile[64][264];  // 33792 B
  const int tid = threadIdx.x;
  const int w = tid >> 6, l = tid & 63, lhi = l >> 4, llo = l & 15;
  const int m0g = blockIdx.x * 64;
  const int m0 = m0g + w * 16;
  f32x4 acc[16];
#pragma unroll
  for (int n = 0; n < 16; ++n) acc[n] = (f32x4){0.f, 0.f, 0.f, 0.f};
  const float* arow = E + (size_t)(m0 + llo) * DDIM;
#pragma unroll
  for (int kd = 0; kd < 8; ++kd) {
    const int dbase = kd * 32 + lhi * 8;
    f32x4 a0 = *(const f32x4*)(arow + dbase);
    f32x4 a1 = *(const f32x4*)(arow + dbase + 4);
    s16x8 af;
#pragma unroll
    for (int j = 0; j < 4; ++j) {
      af[j] = (short)cvt_bf16(a0[j]);
      af[4 + j] = (short)cvt_bf16(a1[j]);
    }
    *(s16x8*)(&tile[w * 16 + llo][dbase]) = af;  // park bf16 row for transpose
#pragma unroll
    for (int n = 0; n < 16; ++n) {
      s16x8 bf = *(const s16x8*)(Wb + (n * 16 + llo) * DDIM + dbase);
      acc[n] = __builtin_amdgcn_mfma_f32_16x16x32_bf16(af, bf, acc[n], 0, 0, 0);
    }
  }
  __syncthreads();
  // transpose out: thread tid owns d = tid; 64 contiguous bf16 -> Vt[b][d][s0..s0+63]
  {
    const int d = tid;
    const int b = m0g >> 12, s0 = m0g & 4095;
    unsigned short* vo = Vt + ((size_t)(b * DDIM) + d) * SDIM + s0;
#pragma unroll
    for (int g = 0; g < 8; ++g) {
      s16x8 pk;
#pragma unroll
      for (int j = 0; j < 8; ++j) pk[j] = (short)tile[g * 8 + j][d];
      *(s16x8*)(vo + g * 8) = pk;
    }
  }
  const float sc = 1.4426950408889634f / 16.0f;  // log2e / sqrt(D)
#pragma unroll
  for (int n = 0; n < 16; ++n) {
#pragma unroll
    for (int r = 0; r < 4; ++r) {
      Kp[(size_t)(m0 + lhi * 4 + r) * DDIM + n * 16 + llo] = cvt_bf16(acc[n][r] * sc);
    }
  }
}

// ---------------- flash attention, causal, interleaved split-KV, static max ----------------
// 256 thr (4 waves); QBLK=64 (wave owns 16 q); KVBLK=32. SINGLE-buffered K+V+P LDS =
// 36864 B -> 4 blocks/CU (16 waves/CU, 2x prior TLP). Two barriers/step; staging latency
// hidden across the 4 independent resident blocks, not within one.
// Swapped MFMA: S^T = mfma(K,Q) (lane col = q); P per-wave LDS 16x64B XOR((q&3)<<4);
// O^T = mfma(V^T,P). V LDS [d 256][32kv] XOR((d&3)<<4) via inverse-swizzled source.
// 1024 equal-work blocks: pair (qt, 63-qt) x 4 batches x 8 chunks; XCD (bid%8) -> 1 batch.
__global__ __launch_bounds__(256, 4) void k_attn(const float* __restrict__ E,
                                                 const unsigned short* __restrict__ Kp,
                                                 const unsigned short* __restrict__ Vt,
                                                 unsigned short* __restrict__ Po,
                                                 float* __restrict__ Lp) {
  __shared__ u32x4 smem4[2304];  // 36864 B: K@0 (16K), V@16K (16K), P@32K (4K)
  char* smem = (char*)smem4;
  const int tid = threadIdx.x;
  const int l = tid & 63, w = tid >> 6, lhi = l >> 4, llo = l & 15;
  // decode: XCD = bid&7 serves one batch
  const int x = blockIdx.x & 7;
  const int b = x >> 1;
  const int j = blockIdx.x >> 3;
  const int p = j >> 2;                       // 0..31
  const int ch = ((j & 3) << 1) | (x & 1);    // 0..7
  const int chb = ch * 4 + b;

  // staging constants (linear LDS dest, inverse-swizzled global source; rule #21)
  const int trow = tid >> 5;                                // K row mod 8
  const int kcolb = ((tid & 31) << 4) ^ ((trow & 7) << 4);  // K source col bytes
  const char* KpB = (const char*)Kp + (size_t)b * SDIM * 512;
  const char* VtB = (const char*)Vt + (size_t)b * DDIM * (SDIM * 2);
  const int d0 = tid >> 2;
  const char* vsrc0 = VtB + (size_t)d0 * 8192 + (((tid & 3) ^ (d0 & 3)) << 4);
  char* sPw = smem + 32768 + w * 1024;  // 16 rows x 64B, per wave
  const int pw_sw = (llo & 3) << 4;     // P XOR
  const int kr_sw = (llo & 7) << 4;     // K read XOR

  for (int c2 = 0; c2 < 2; ++c2) {
    const int qt = c2 ? (63 - p) : p;
    const int q0 = qt * 64;
    const int ntile = 2 * (qt + 1);  // kv tiles of 32
    if (ntile <= ch) continue;       // empty ctx (merge's cnt skips this layer)
    const int nst = (ntile - ch + NCH - 1) / NCH;
    const int q = q0 + w * 16 + llo;  // this lane's q column

    // Q fragments (B-operand): lane col q, k-elems d = kd*32 + lhi*8 + j
    s16x8 qf[8];
    {
      const float* Eq = E + ((size_t)(b * SDIM) + q) * DDIM;
#pragma unroll
      for (int kd = 0; kd < 8; ++kd) {
        f32x4 a0 = *(const f32x4*)(Eq + kd * 32 + lhi * 8);
        f32x4 a1 = *(const f32x4*)(Eq + kd * 32 + lhi * 8 + 4);
#pragma unroll
        for (int jj = 0; jj < 4; ++jj) {
          qf[kd][jj] = (short)cvt_bf16(a0[jj]);
          qf[kd][4 + jj] = (short)cvt_bf16(a1[jj]);
        }
      }
    }

    f32x4 oT[16];
#pragma unroll
    for (int n = 0; n < 16; ++n) oT[n] = (f32x4){0.f, 0.f, 0.f, 0.f};
    float lsum = 0.f;

    for (int t = 0; t < nst; ++t) {
      const int kv0 = (ch + NCH * t) * 32;

      __syncthreads();  // all waves done reading previous tile
      {  // stage K (16KB) + V (16KB), single buffer
        const char* ks = KpB + (size_t)(kv0 + trow) * 512 + kcolb;
#pragma unroll
        for (int i = 0; i < 4; ++i)
          GLOAD_LDS16(ks + (size_t)i * 4096, smem + i * 4096 + tid * 16);
        const char* vs = vsrc0 + (size_t)kv0 * 2;
#pragma unroll
        for (int i = 0; i < 4; ++i)
          GLOAD_LDS16(vs + (size_t)i * 524288, smem + 16384 + i * 4096 + tid * 16);
      }
      __syncthreads();  // publish (drains vmcnt)

      // S^T = mfma(K, Q): rows = 32 kv (2 kb-groups), col = q; 2 interleaved chains
      f32x4 sa[2];
      sa[0] = (f32x4){0.f, 0.f, 0.f, 0.f};
      sa[1] = (f32x4){0.f, 0.f, 0.f, 0.f};
      const char* krow0 = smem + llo * 512;
      __builtin_amdgcn_s_setprio(1);
#pragma unroll
      for (int kd = 0; kd < 8; ++kd) {
        const int off = (kd * 64 + lhi * 16) ^ kr_sw;
        s16x8 k0 = *(const s16x8*)(krow0 + off);
        s16x8 k1 = *(const s16x8*)(krow0 + 8192 + off);  // kb=1: rows +16 (16*512)
        sa[0] = __builtin_amdgcn_mfma_f32_16x16x32_bf16(k0, qf[kd], sa[0], 0, 0, 0);
        sa[1] = __builtin_amdgcn_mfma_f32_16x16x32_bf16(k1, qf[kd], sa[1], 0, 0, 0);
      }
      __builtin_amdgcn_s_setprio(0);

      // softmax (static max; log2e folded in Kp) + mask on diagonal tiles, pack to P
      const bool diag = (kv0 + 32 > q0);
#pragma unroll
      for (int kb = 0; kb < 2; ++kb) {
        const int kvr = kv0 + kb * 16 + lhi * 4;
        float pv[4];
#pragma unroll
        for (int rr = 0; rr < 4; ++rr) {
          float v = exp2f(sa[kb][rr] - 32.0f);
          if (diag && (kvr + rr > q)) v = 0.0f;
          pv[rr] = v;
        }
        lsum += (pv[0] + pv[1]) + (pv[2] + pv[3]);
        unsigned int w0 = __builtin_amdgcn_perm(__float_as_uint(pv[1]),
                                                __float_as_uint(pv[0]), 0x07060302u);
        unsigned int w1 = __builtin_amdgcn_perm(__float_as_uint(pv[3]),
                                                __float_as_uint(pv[2]), 0x07060302u);
        *(uint2*)(sPw + llo * 64 + ((kb * 32 + lhi * 8) ^ pw_sw)) = make_uint2(w0, w1);
      }

      // O^T += mfma(V^T, P): per-wave P (in-wave lgkmcnt only); 16 indep chains
      s16x8 pa = *(const s16x8*)(sPw + llo * 64 +
                                 (((lhi >> 1) * 32 + (lhi & 1) * 16) ^ pw_sw));
      const char* vb_ = smem + 16384;
      __builtin_amdgcn_s_setprio(1);
#pragma unroll
      for (int n = 0; n < 16; ++n) {
        const int d = n * 16 + llo;
        s16x8 vf = *(const s16x8*)(vb_ + d * 64 + ((lhi << 4) ^ ((d & 3) << 4)));
        oT[n] = __builtin_amdgcn_mfma_f32_16x16x32_bf16(vf, pa, oT[n], 0, 0, 0);
      }
      __builtin_amdgcn_s_setprio(0);
    }

    // epilogue: reduce l across lhi groups; store unnormalized O^T (bf16) + l (f32)
    lsum += __shfl_xor(lsum, 16);
    lsum += __shfl_xor(lsum, 32);
    unsigned short* PoW = Po + ((size_t)chb * SDIM + q) * DDIM;
#pragma unroll
    for (int n = 0; n < 16; ++n) {
      unsigned int w0 = (unsigned int)cvt_bf16(oT[n][0]) |
                        ((unsigned int)cvt_bf16(oT[n][1]) << 16);
      unsigned int w1 = (unsigned int)cvt_bf16(oT[n][2]) |
                        ((unsigned int)cvt_bf16(oT[n][3]) << 16);
      *(uint2*)(PoW + n * 16 + lhi * 4) = make_uint2(w0, w1);
    }
    if (lhi == 0) Lp[(size_t)chb * SDIM + q] = lsum;
  }
}

// ---------------- merge: out = sum(o_c) / sum(l_c), skipping empty layers ---------------
__global__ __launch_bounds__(256) void k_merge(const unsigned short* __restrict__ Po,
                                               const float* __restrict__ Lp,
                                               float* __restrict__ out) {
  const size_t e = ((size_t)blockIdx.x * 256 + threadIdx.x) * 8;
  const size_t f = e >> 8;
  const int s = (int)(f & 4095);
  const int cnt = min(NCH, 2 * (s >> 6) + 2);  // chunks with work for this 64-row q-tile
  float lt = 0.f;
  for (int c = 0; c < cnt; ++c) lt += Lp[(size_t)c * 16384 + f];
  const float inv = 1.0f / lt;
  float acc[8] = {0.f, 0.f, 0.f, 0.f, 0.f, 0.f, 0.f, 0.f};
  for (int c = 0; c < cnt; ++c) {
    s16x8 a = *(const s16x8*)(Po + (size_t)c * 4194304 + e);
#pragma unroll
    for (int jj = 0; jj < 8; ++jj) acc[jj] += bf2f((unsigned short)a[jj]);
  }
  f32x4 o0, o1;
#pragma unroll
  for (int jj = 0; jj < 4; ++jj) {
    o0[jj] = acc[jj] * inv;
    o1[jj] = acc[4 + jj] * inv;
  }
  *(f32x4*)(out + e) = o0;
  *(f32x4*)(out + e + 4) = o1;
}

extern "C" void kernel_launch(void* const* d_in, const int* in_sizes, int n_in,
                              void* d_out, int out_size, void* d_ws, size_t ws_size,
                              hipStream_t stream) {
  (void)in_sizes; (void)n_in; (void)out_size; (void)ws_size;
  const float* E = (const float*)d_in[0];
  const float* W = (const float*)d_in[1];
  float* out = (float*)d_out;
  char* ws = (char*)d_ws;

  unsigned short* Kp = (unsigned short*)(ws);                // 8 MB bf16 (B*S, D), scaled
  unsigned short* Vt = (unsigned short*)(ws + 8388608);      // 8 MB bf16 per-batch [D][S]
  unsigned short* Po = (unsigned short*)(ws + 16777216);     // 64 MB bf16 partials [32][S][D]
  float* Lp = (float*)(ws + 83886080);                       // 512 KB f32 [32][S]
  unsigned short* Wb = (unsigned short*)(ws + 84410368);     // 128 KB bf16 W

  k_convw<<<dim3(32), dim3(256), 0, stream>>>(W, Wb);
  k_projv<<<dim3(256), dim3(256), 0, stream>>>(E, Wb, Kp, Vt);
  k_attn<<<dim3(1024), dim3(256), 0, stream>>>(E, Kp, Vt, Po, Lp);
  k_merge<<<dim3(2048), dim3(256), 0, stream>>>(Po, Lp, out);
}